// Round 8
// baseline (10136.427 us; speedup 1.0000x reference)
//
#include <hip/hip_runtime.h>
#include <hip/hip_bf16.h>
#include <stdint.h>

typedef __bf16 bf16_t;
typedef bf16_t bf16x8 __attribute__((ext_vector_type(8)));
typedef float  f32x4  __attribute__((ext_vector_type(4)));
typedef float  f32x16 __attribute__((ext_vector_type(16)));

#define I_DIM 512
#define H_DIM 1024
#define B_DIM 64
#define S_DIM 512
#define G4    4096   // 4*H
#define CHUNK 32     // steps per chunk
#define NCHUNK (S_DIM / CHUNK)

// ---------------- workspace layout (bytes) — total ~50 MB ----------------
#define O_WXT   0x0000000ULL  // [4096][512]  bf16 = 4 MB
#define O_WHT   0x0400000ULL  // [4096][1024] bf16 = 8 MB
#define O_BIAS  0x0C00000ULL  // [4096] f32 = 16 KB
#define O_CST   0x0C10000ULL  // [64][1024] f32 = 256 KB
#define O_FLAGS 0x0C50000ULL  // 256 arrival flags, 16B-spaced = 4 KB
#define O_MAIL  0x0C60000ULL  // 256 mailboxes 64B-spaced (16 KB) + heat cell at +64 KB
#define O_HBUF  0x0D00000ULL  // 33 ring buffers * 128 KB (A-frag order) = 4.125 MB
#define O_XP    0x1200000ULL  // ring: 2 x [CHUNK*64][4096] bf16 = 32 MB

__device__ __forceinline__ float sigm(float x)      { return 1.f / (1.f + __expf(-x)); }
__device__ __forceinline__ float tanh_fast(float x) { return 1.f - 2.f / (__expf(2.f * x) + 1.f); }

__device__ __forceinline__ void st_u32_llc(uint32_t* p, uint32_t v) {
    __hip_atomic_store(p, v, __ATOMIC_RELAXED, __HIP_MEMORY_SCOPE_AGENT);
}
__device__ __forceinline__ void st_u64_llc(uint64_t* p, uint64_t v) {
    __hip_atomic_store(p, v, __ATOMIC_RELAXED, __HIP_MEMORY_SCOPE_AGENT);
}
__device__ __forceinline__ uint32_t ld_u32_llc(const uint32_t* p) {
    return __hip_atomic_load(p, __ATOMIC_RELAXED, __HIP_MEMORY_SCOPE_AGENT);
}

// Packed gate-column permutation: packed col p = q*32 + g*8 + jj  <->  hidden j = q*8+jj, gate g (0:i 1:f 2:g 3:o)

__global__ void k_pack_wx(const float* __restrict__ w0, const float* __restrict__ w1,
                          const float* __restrict__ w2, const float* __restrict__ w3,
                          bf16_t* __restrict__ wxt) {
    int tid = blockIdx.x * 256 + threadIdx.x;
    int k = tid >> 12;
    int p = tid & 4095;
    int q = p >> 5, g = (p >> 3) & 3, jj = p & 7;
    int j = q * 8 + jj;
    const float* src = (g == 0) ? w0 : (g == 1) ? w1 : (g == 2) ? w2 : w3;
    wxt[(size_t)p * I_DIM + k] = (bf16_t)src[k * H_DIM + j];
}

__global__ void k_pack_wh(const float* __restrict__ w0, const float* __restrict__ w1,
                          const float* __restrict__ w2, const float* __restrict__ w3,
                          bf16_t* __restrict__ wht) {
    int tid = blockIdx.x * 256 + threadIdx.x;
    int k = tid >> 12;
    int p = tid & 4095;
    int q = p >> 5, g = (p >> 3) & 3, jj = p & 7;
    int j = q * 8 + jj;
    const float* src = (g == 0) ? w0 : (g == 1) ? w1 : (g == 2) ? w2 : w3;
    wht[(size_t)p * H_DIM + k] = (bf16_t)src[k * H_DIM + j];
}

__global__ void k_pack_bias(const float* bi0, const float* bh0, const float* bi1, const float* bh1,
                            const float* bi2, const float* bh2, const float* bi3, const float* bh3,
                            float* __restrict__ bias) {
    int p = blockIdx.x * 256 + threadIdx.x;
    int q = p >> 5, g = (p >> 3) & 3, jj = p & 7;
    int j = q * 8 + jj;
    const float* a = (g == 0) ? bi0 : (g == 1) ? bi1 : (g == 2) ? bi2 : bi3;
    const float* b = (g == 0) ? bh0 : (g == 1) ? bh1 : (g == 2) ? bh2 : bh3;
    bias[p] = a[j] + b[j];
}

// ---------------- prologue x_proj GEMM (chunk 0 only) ----------------
__global__ __launch_bounds__(256, 2) void k_xproj(
    const float* __restrict__ x, const bf16_t* __restrict__ wxt,
    const float* __restrict__ bias, bf16_t* __restrict__ xp, int r_base)
{
    __shared__ __align__(16) bf16_t Al[8 * 64 * 8];
    __shared__ __align__(16) bf16_t Bl[8 * 64 * 8];
    const int tid = threadIdx.x;
    const int n0 = blockIdx.x * 128;
    const int r0 = r_base + blockIdx.y * 128;
    const int wv = tid >> 6;
    const int lane = tid & 63;
    const int mq = wv >> 1, nq = wv & 1;
    f32x4 acc[4][4] = {};

    for (int kk = 0; kk < I_DIM; kk += 32) {
        __syncthreads();
        #pragma unroll
        for (int sidx = 0; sidx < 2; ++sidx) {
            int s = tid + sidx * 256;
            int mt = s >> 6, l = s & 63;
            int m = l & 15, kb = (l >> 4) * 8;
            int r = r0 + mt * 16 + m;
            int b = r & 63, si = r >> 6;
            const float* gp = x + ((size_t)(b * S_DIM + si)) * I_DIM + kk + kb;
            float4 v0 = *(const float4*)gp;
            float4 v1 = *(const float4*)(gp + 4);
            bf16x8 a;
            a[0] = (bf16_t)v0.x; a[1] = (bf16_t)v0.y; a[2] = (bf16_t)v0.z; a[3] = (bf16_t)v0.w;
            a[4] = (bf16_t)v1.x; a[5] = (bf16_t)v1.y; a[6] = (bf16_t)v1.z; a[7] = (bf16_t)v1.w;
            *(bf16x8*)&Al[s * 8] = a;
            bf16x8 bv = *(const bf16x8*)(wxt + (size_t)(n0 + mt * 16 + m) * I_DIM + kk + kb);
            *(bf16x8*)&Bl[s * 8] = bv;
        }
        __syncthreads();
        bf16x8 af[4], bfr[4];
        #pragma unroll
        for (int mt = 0; mt < 4; ++mt) af[mt]  = *(bf16x8*)&Al[((mq * 4 + mt) * 64 + lane) * 8];
        #pragma unroll
        for (int nt = 0; nt < 4; ++nt) bfr[nt] = *(bf16x8*)&Bl[((nq * 4 + nt) * 64 + lane) * 8];
        #pragma unroll
        for (int mt = 0; mt < 4; ++mt)
            #pragma unroll
            for (int nt = 0; nt < 4; ++nt)
                acc[mt][nt] = __builtin_amdgcn_mfma_f32_16x16x32_bf16(af[mt], bfr[nt], acc[mt][nt], 0, 0, 0);
    }
    const int l15 = lane & 15, quad = lane >> 4;
    #pragma unroll
    for (int nt = 0; nt < 4; ++nt) {
        int col = n0 + nq * 64 + nt * 16 + l15;
        float bv = bias[col];
        #pragma unroll
        for (int mt = 0; mt < 4; ++mt)
            #pragma unroll
            for (int r = 0; r < 4; ++r) {
                int row = r0 - r_base + mq * 64 + mt * 16 + quad * 4 + r;
                xp[(size_t)row * G4 + col] = (bf16_t)(acc[mt][nt][r] + bv);
            }
    }
}

// ---------------- persistent recurrent kernel (one chunk of CHUNK steps) ----------------
// Grid = 320 WGs x 64 thr:
//   wg 0..255   workers (q = wg&127, bh = wg>>7)          — R6 structure, proven correct
//   wg 256,257  per-half barrier aggregators
//   wg 258..319 HEATERS: compute next chunk's x_proj into the xp ring, then
//               dummy-MFMA spin until chunk done. Purpose: R2-R7 all bottomed
//               at ~10-16 us/step with every pipe <4% busy — consistent with
//               DVFS downclocking (~2x) on a near-idle chip. Heaters keep
//               ~25% of CUs MFMA-busy for the whole chunk to pin clocks, and
//               absorb the 16 serial k_xproj launches as a bonus.
// Workers s_setprio 2, heaters s_setprio 0 (arbitration where co-resident).
// LDS 66 KB/WG -> 2 WGs/CU -> all 320 resident (no deadlock).
__global__ __launch_bounds__(64, 1) void k_lstm(
    const bf16_t* __restrict__ wht, const float* __restrict__ x,
    const bf16_t* __restrict__ wxt, const float* __restrict__ bias,
    bf16_t* __restrict__ xpring,
    bf16_t* __restrict__ hbuf, float* __restrict__ cstbuf,
    float* __restrict__ out, unsigned* __restrict__ flags,
    unsigned* __restrict__ mail, int chunk_id)
{
    __shared__ __align__(16) bf16_t Blds[33024];   // 64 KB B-frags + 512 B Hlds overlay
    const int lane = threadIdx.x;
    const int wg = blockIdx.x;
    const int t0 = chunk_id * CHUNK;

    if (wg >= 258) {
        // ================= HEATER =================
        asm volatile("s_setprio 0");
        const int hid = wg - 258;            // 0..61
        const int cn = chunk_id + 1;
        bf16_t* Al = Blds;                   // 4 KB overlay
        bf16_t* Bl = Blds + 2048;
        if (cn < NCHUNK) {
            bf16_t* xpn = xpring + (size_t)(cn & 1) * ((size_t)CHUNK * 64 * G4);
            for (int tk = hid; tk < 2048; tk += 62) {   // 32 steps x 64 col-blocks
                int s  = tk >> 6;
                int n0 = (tk & 63) * 64;
                int si = cn * CHUNK + s;
                f32x4 acc[4][4] = {};
                for (int kk = 0; kk < I_DIM; kk += 32) {
                    #pragma unroll
                    for (int mt = 0; mt < 4; ++mt) {
                        int m = lane & 15, kb = (lane >> 4) * 8;
                        int b = mt * 16 + m;
                        const float* gp = x + ((size_t)(b * S_DIM + si)) * I_DIM + kk + kb;
                        float4 v0 = *(const float4*)gp;
                        float4 v1 = *(const float4*)(gp + 4);
                        bf16x8 a;
                        a[0] = (bf16_t)v0.x; a[1] = (bf16_t)v0.y; a[2] = (bf16_t)v0.z; a[3] = (bf16_t)v0.w;
                        a[4] = (bf16_t)v1.x; a[5] = (bf16_t)v1.y; a[6] = (bf16_t)v1.z; a[7] = (bf16_t)v1.w;
                        *(bf16x8*)&Al[(mt * 64 + lane) * 8] = a;
                        bf16x8 bv = *(const bf16x8*)(wxt + (size_t)(n0 + mt * 16 + m) * I_DIM + kk + kb);
                        *(bf16x8*)&Bl[(mt * 64 + lane) * 8] = bv;
                    }
                    asm volatile("s_waitcnt lgkmcnt(0)" ::: "memory");
                    bf16x8 af[4], bfr[4];
                    #pragma unroll
                    for (int i2 = 0; i2 < 4; ++i2) {
                        af[i2]  = *(bf16x8*)&Al[(i2 * 64 + lane) * 8];
                        bfr[i2] = *(bf16x8*)&Bl[(i2 * 64 + lane) * 8];
                    }
                    #pragma unroll
                    for (int mt = 0; mt < 4; ++mt)
                        #pragma unroll
                        for (int nt = 0; nt < 4; ++nt)
                            acc[mt][nt] = __builtin_amdgcn_mfma_f32_16x16x32_bf16(af[mt], bfr[nt], acc[mt][nt], 0, 0, 0);
                }
                const int m = lane & 15, quad = lane >> 4;
                #pragma unroll
                for (int nt = 0; nt < 4; ++nt) {
                    int colp = n0 + nt * 16 + m;
                    float bv = bias[colp];
                    #pragma unroll
                    for (int mt = 0; mt < 4; ++mt)
                        #pragma unroll
                        for (int r = 0; r < 4; ++r) {
                            int row = mt * 16 + quad * 4 + r;
                            xpn[(size_t)(s * 64 + row) * G4 + colp] = (bf16_t)(acc[mt][nt][r] + bv);
                        }
                }
            }
        }
        // dummy-MFMA heat spin until this chunk's barrier sequence completes
        {
            unsigned tv = (unsigned)(t0 + CHUNK - 1);
            unsigned* heat = mail + 16384;   // dedicated cell, no worker reads it
            f32x4 hacc = {};
            bf16x8 ha = {};
            int guard = 200000;
            for (;;) {
                #pragma unroll 4
                for (int i2 = 0; i2 < 1024; ++i2)
                    hacc = __builtin_amdgcn_mfma_f32_16x16x32_bf16(ha, ha, hacc, 0, 0, 0);
                unsigned mv = ld_u32_llc(heat);
                if (mv >= tv || --guard == 0) break;
            }
            if (hacc[0] == 1234.5678f) ((float*)xpring)[0] = hacc[0];  // defeat DCE (never true)
        }
        return;
    }

    if (wg >= 256) {
        // ================= AGGREGATOR for batch half a =================
        asm volatile("s_setprio 1");
        const int a = wg - 256;
        unsigned* fl = flags + (size_t)a * 512;   // 128 slots, 16B-spaced
        unsigned* ml = mail  + (size_t)a * 2048;  // 128 slots, 64B-spaced
        for (int tl = 0; tl + 1 < CHUNK; ++tl) {
            unsigned tv = (unsigned)(t0 + tl + 1);
            int guard = 2000000;
            for (;;) {
                unsigned f0 = ld_u32_llc(fl + lane * 4);
                unsigned f1 = ld_u32_llc(fl + (lane + 64) * 4);
                int ok = (f0 >= tv) && (f1 >= tv);
                if (__all(ok) || --guard == 0) break;
                __builtin_amdgcn_s_sleep(1);
            }
            st_u32_llc(ml + lane * 16, tv);
            st_u32_llc(ml + (lane + 64) * 16, tv);
        }
        if (a == 0 && lane == 0)
            st_u32_llc(mail + 16384, (unsigned)(t0 + CHUNK - 1));  // release heaters
        return;
    }

    // ================= WORKER =================
    const int q  = wg & 127;
    const int bh = wg >> 7;
    const bf16_t* xp = xpring + (size_t)(chunk_id & 1) * ((size_t)CHUNK * 64 * G4);
    bf16_t* Hlds = Blds + 32768;

    // Stage WhT rows q*32..+31 into LDS in 32x32x16 B-fragment order.
    for (int i = 0; i < 64; ++i) {
        int task = lane + (i << 6);
        int c = task >> 7;
        int k = (task & 127) << 3;
        bf16x8 v = *(const bf16x8*)(wht + (((size_t)(q * 32 + c)) << 10) + k);
        int base = (((k >> 4) << 6) + c + (((k >> 3) & 1) << 5)) << 3;
        *(bf16x8*)&Blds[base] = v;
    }
    __syncthreads();
    asm volatile("s_setprio 2");

    const int col  = lane & 31;
    const int ksel = lane >> 5;
    const int gt   = (lane >> 3) & 3;  // 0:i 1:f 2:g 3:o
    const int jj   = lane & 7;

    int rrow[16];
    #pragma unroll
    for (int r = 0; r < 16; ++r) rrow[r] = (r & 3) + 8 * (r >> 2) + 4 * ksel;

    float cst[16];
    if (t0 == 0) {
        #pragma unroll
        for (int r = 0; r < 16; ++r) cst[r] = 0.f;
    } else {
        #pragma unroll
        for (int r = 0; r < 16; ++r)
            cst[r] = cstbuf[(bh * 32 + rrow[r]) * H_DIM + q * 8 + jj];
    }

    bf16_t xpr[16];
    #pragma unroll
    for (int r = 0; r < 16; ++r)
        xpr[r] = xp[(size_t)(bh * 32 + rrow[r]) * G4 + q * 32 + col];

    const int hw_off = (bh << 13) + ((q >> 1) << 7) + ((q & 1) << 6) + lane;
    unsigned* myflag = flags + (size_t)(bh * 128 + q) * 4;
    unsigned* mymail = mail  + (size_t)(bh * 128 + q) * 16;

    for (int tl = 0; tl < CHUNK; ++tl) {
        const int t = t0 + tl;
        const int rd = (tl == 0) ? ((t0 == 0) ? 0 : 32) : tl;
        const bf16_t* ab = hbuf + ((size_t)rd << 16) + (bh << 15) + (lane << 3);

        bf16x8 afr[8];
        #pragma unroll
        for (int i = 0; i < 8; ++i) afr[i] = *(const bf16x8*)(ab + i * 512);
        f32x16 acc0 = {}, acc1 = {}, acc2 = {}, acc3 = {};
        #pragma unroll
        for (int ks = 0; ks < 64; ++ks) {
            bf16x8 a = afr[ks & 7];
            if (ks < 56) afr[ks & 7] = *(const bf16x8*)(ab + (ks + 8) * 512);
            bf16x8 b = *(const bf16x8*)&Blds[((ks << 6) + lane) << 3];
            if ((ks & 3) == 0)      acc0 = __builtin_amdgcn_mfma_f32_32x32x16_bf16(a, b, acc0, 0, 0, 0);
            else if ((ks & 3) == 1) acc1 = __builtin_amdgcn_mfma_f32_32x32x16_bf16(a, b, acc1, 0, 0, 0);
            else if ((ks & 3) == 2) acc2 = __builtin_amdgcn_mfma_f32_32x32x16_bf16(a, b, acc2, 0, 0, 0);
            else                    acc3 = __builtin_amdgcn_mfma_f32_32x32x16_bf16(a, b, acc3, 0, 0, 0);
        }
        f32x16 accs = acc0 + acc1 + acc2 + acc3;

        float act[16];
        #pragma unroll
        for (int r = 0; r < 16; ++r) {
            float pre = accs[r] + (float)xpr[r];
            act[r] = (gt == 2) ? tanh_fast(pre) : sigm(pre);
        }

        #pragma unroll
        for (int r = 0; r < 16; ++r) {
            float fv = __shfl_xor(act[r], 8, 64);
            float gv = __shfl_xor(act[r], 16, 64);
            float ov = __shfl_xor(act[r], 24, 64);
            if (gt == 0) {
                float cn = fv * cst[r] + act[r] * gv;
                cst[r] = cn;
                float hv = ov * tanh_fast(cn);
                Hlds[rrow[r] * 8 + jj] = (bf16_t)hv;
                if (t == S_DIM - 1) {
                    int rowg = bh * 32 + rrow[r];
                    int j = q * 8 + jj;
                    out[rowg * H_DIM + j] = hv;            // h_T
                    out[65536 + rowg * H_DIM + j] = cn;    // c_T
                }
            }
        }
        asm volatile("s_waitcnt lgkmcnt(0)" ::: "memory");

        // one coalesced write-through store per wave: 512 B h-slice
        {
            uint64_t v = *(const uint64_t*)&Hlds[lane * 4];
            uint64_t* hwn = (uint64_t*)hbuf + ((size_t)(tl + 1) << 14) + hw_off;
            st_u64_llc(hwn, v);
        }

        if (tl < CHUNK - 1) {
            unsigned tv = (unsigned)(t + 1);
            asm volatile("s_waitcnt vmcnt(0)" ::: "memory");
            st_u32_llc(myflag, tv);
            #pragma unroll
            for (int r = 0; r < 16; ++r)
                xpr[r] = xp[(size_t)((tl + 1) * 64 + bh * 32 + rrow[r]) * G4 + q * 32 + col];
            int guard = 1000000;
            for (;;) {
                unsigned m = ld_u32_llc(mymail);
                if (m >= tv || --guard == 0) break;
                __builtin_amdgcn_s_sleep(1);
            }
            __builtin_amdgcn_fence(__ATOMIC_ACQUIRE, "wavefront");
        }
    }

    if (gt == 0) {
        #pragma unroll
        for (int r = 0; r < 16; ++r)
            cstbuf[(bh * 32 + rrow[r]) * H_DIM + q * 8 + jj] = cst[r];
    }
}

extern "C" void kernel_launch(void* const* d_in, const int* in_sizes, int n_in,
                              void* d_out, int out_size, void* d_ws, size_t ws_size,
                              hipStream_t stream) {
    const float* x   = (const float*)d_in[0];
    const float* wii = (const float*)d_in[1];
    const float* bii = (const float*)d_in[2];
    const float* whi = (const float*)d_in[3];
    const float* bhi = (const float*)d_in[4];
    const float* wif = (const float*)d_in[5];
    const float* bif = (const float*)d_in[6];
    const float* whf = (const float*)d_in[7];
    const float* bhf = (const float*)d_in[8];
    const float* wig = (const float*)d_in[9];
    const float* big = (const float*)d_in[10];
    const float* whg = (const float*)d_in[11];
    const float* bhg = (const float*)d_in[12];
    const float* wio = (const float*)d_in[13];
    const float* bio = (const float*)d_in[14];
    const float* who = (const float*)d_in[15];
    const float* bho = (const float*)d_in[16];

    char* ws = (char*)d_ws;
    bf16_t*  wxt   = (bf16_t*)(ws + O_WXT);
    bf16_t*  wht   = (bf16_t*)(ws + O_WHT);
    float*   bias  = (float*)(ws + O_BIAS);
    float*   cstb  = (float*)(ws + O_CST);
    unsigned* flags = (unsigned*)(ws + O_FLAGS);
    unsigned* mail  = (unsigned*)(ws + O_MAIL);
    bf16_t*  hbuf  = (bf16_t*)(ws + O_HBUF);
    bf16_t*  xpring = (bf16_t*)(ws + O_XP);

    hipMemsetAsync(hbuf, 0, 128 * 1024, stream);            // h0 = 0 (ring slot 0)
    hipMemsetAsync(flags, 0, 4096, stream);
    hipMemsetAsync(mail, 0, 16384 + 65600, stream);         // mailboxes + heat cell

    k_pack_wx<<<8192, 256, 0, stream>>>(wii, wif, wig, wio, wxt);
    k_pack_wh<<<16384, 256, 0, stream>>>(whi, whf, whg, who, wht);
    k_pack_bias<<<16, 256, 0, stream>>>(bii, bhi, bif, bhf, big, bhg, bio, bho, bias);
    k_xproj<<<dim3(32, CHUNK * 64 / 128), 256, 0, stream>>>(x, wxt, bias, xpring, 0);  // chunk 0

    float* out = (float*)d_out;
    for (int c = 0; c < NCHUNK; ++c) {
        k_lstm<<<320, 64, 0, stream>>>(wht, x, wxt, bias, xpring,
                                       hbuf, cstb, out, flags, mail, c);
    }
}